// Round 4
// baseline (37.907 us; speedup 1.0000x reference)
//
#include <hip/hip_runtime.h>
#include <hip/hip_bf16.h>

// Problem constants
#define BB 32   // batch
#define NN 512  // ragged items (reduced axis)
#define SS 32   // static input size (rows per token tile)
#define WW 64   // attention layer width (K of GEMM1, also hidden width)
#define PP 64   // layer param (output features)

#define NCHUNK 16              // n's per block
#define CHB    (NN / NCHUNK)   // 32 chunks per b

typedef __attribute__((ext_vector_type(8))) short bf16x8;  // 8 bf16 (4 VGPRs)
typedef __attribute__((ext_vector_type(4))) float f32x4;   // MFMA acc / vec loads

// f32 -> bf16 bits via native cast; compiler fuses pairs into v_cvt_pk_bf16_f32
__device__ __forceinline__ short f2bf(float v) {
    __hip_bfloat16 h = __float2bfloat16(v);
    return __builtin_bit_cast(short, h);
}

// Kernel 1: part[bid][s][w] = sum_{n in chunk} relu(x[b,n,s,:] @ W1[:,w] + b1[w])
// grid = BB*CHB = 1024 blocks, 256 threads (4 waves). Each wave: 4 tokens.
__global__ __launch_bounds__(256) void pool1(const float* __restrict__ x,
                                             const float* __restrict__ W1,
                                             const float* __restrict__ b1,
                                             float* __restrict__ part) {
    const int tid   = threadIdx.x;
    const int wv    = tid >> 6;       // wave 0..3
    const int lane  = tid & 63;
    const int g     = lane >> 4;      // lane group 0..3
    const int q     = lane & 15;
    const int b     = blockIdx.x >> 5;     // CHB == 32
    const int chunk = blockIdx.x & 31;

    // W1 fragments (B operand): wfrag[nt][ks] elem j = W1[ks*32+g*8+j][nt*16+q]
    bf16x8 wfrag[4][2];
#pragma unroll
    for (int nt = 0; nt < 4; ++nt) {
#pragma unroll
        for (int ks = 0; ks < 2; ++ks) {
            bf16x8 f;
#pragma unroll
            for (int j = 0; j < 8; ++j)
                f[j] = f2bf(W1[(ks * 32 + g * 8 + j) * WW + nt * 16 + q]);
            wfrag[nt][ks] = f;
        }
    }

    // bias folded into MFMA C-init: D-elem (reg r) has col = nt*16+q -> same bias all r
    f32x4 biasv[4];
#pragma unroll
    for (int nt = 0; nt < 4; ++nt) {
        float bv = b1[nt * 16 + q];
        biasv[nt] = (f32x4){bv, bv, bv, bv};
    }

    f32x4 hrun[2][4];
#pragma unroll
    for (int mt = 0; mt < 2; ++mt)
#pragma unroll
        for (int nt = 0; nt < 4; ++nt)
            hrun[mt][nt] = (f32x4){0.f, 0.f, 0.f, 0.f};

    const int n0 = chunk * NCHUNK + wv * 4;
#pragma unroll
    for (int t = 0; t < 4; ++t) {
        const float* rowbase = x + ((size_t)(b * NN + n0 + t)) * (SS * WW);
        // A fragments: afrag[mt][ks] elem j = x[row = mt*16+q][col = ks*32+g*8+j]
        bf16x8 afrag[2][2];
#pragma unroll
        for (int mt = 0; mt < 2; ++mt) {
#pragma unroll
            for (int ks = 0; ks < 2; ++ks) {
                const f32x4* p = reinterpret_cast<const f32x4*>(
                    rowbase + (mt * 16 + q) * WW + ks * 32 + g * 8);
                f32x4 v0 = __builtin_nontemporal_load(p);
                f32x4 v1 = __builtin_nontemporal_load(p + 1);
                bf16x8 f;
                f[0] = f2bf(v0[0]); f[1] = f2bf(v0[1]); f[2] = f2bf(v0[2]); f[3] = f2bf(v0[3]);
                f[4] = f2bf(v1[0]); f[5] = f2bf(v1[1]); f[6] = f2bf(v1[2]); f[7] = f2bf(v1[3]);
                afrag[mt][ks] = f;
            }
        }
#pragma unroll
        for (int mt = 0; mt < 2; ++mt) {
#pragma unroll
            for (int nt = 0; nt < 4; ++nt) {
                f32x4 acc = biasv[nt];   // C = bias
                acc = __builtin_amdgcn_mfma_f32_16x16x32_bf16(afrag[mt][0], wfrag[nt][0], acc, 0, 0, 0);
                acc = __builtin_amdgcn_mfma_f32_16x16x32_bf16(afrag[mt][1], wfrag[nt][1], acc, 0, 0, 0);
#pragma unroll
                for (int r = 0; r < 4; ++r)
                    hrun[mt][nt][r] += fmaxf(acc[r], 0.f);
            }
        }
    }

    // cross-wave reduce in LDS, then vectorized plain stores (no atomics)
    __shared__ float lds[4][SS * WW];
#pragma unroll
    for (int mt = 0; mt < 2; ++mt)
#pragma unroll
        for (int nt = 0; nt < 4; ++nt)
#pragma unroll
            for (int r = 0; r < 4; ++r)
                lds[wv][(mt * 16 + g * 4 + r) * WW + nt * 16 + q] = hrun[mt][nt][r];
    __syncthreads();

    float* dst = part + (size_t)blockIdx.x * (SS * WW);
#pragma unroll
    for (int k = 0; k < 2; ++k) {
        const int idx = tid * 4 + k * 1024;
        f32x4 v0 = *reinterpret_cast<const f32x4*>(&lds[0][idx]);
        f32x4 v1 = *reinterpret_cast<const f32x4*>(&lds[1][idx]);
        f32x4 v2 = *reinterpret_cast<const f32x4*>(&lds[2][idx]);
        f32x4 v3 = *reinterpret_cast<const f32x4*>(&lds[3][idx]);
        f32x4 s = (v0 + v1) + (v2 + v3);
        __builtin_nontemporal_store(s, reinterpret_cast<f32x4*>(&dst[idx]));
    }
}

// Kernel 2: out[b,s,p] = sum_w (sum_c part[b*32+c][s][w]) * W2[w,p] + NN * b2[p]
// grid = 1024 blocks (one per output row), 256 threads: 4 waves split the
// 32-chunk reduction, wave 0 does the 64x64 matvec.
__global__ __launch_bounds__(256) void pool2(const float* __restrict__ part,
                                             const float* __restrict__ W2,
                                             const float* __restrict__ b2,
                                             float* __restrict__ out) {
    const int tid  = threadIdx.x;
    const int wv   = tid >> 6;
    const int lane = tid & 63;
    const int row  = blockIdx.x;        // b*SS + s
    const int b    = row >> 5;          // SS == 32
    const int s    = row & 31;

    const float* pb = part + ((size_t)b * CHB) * (SS * WW) + s * WW + lane;
    float h = 0.f;
#pragma unroll
    for (int c = 0; c < CHB / 4; ++c)
        h += __builtin_nontemporal_load(&pb[(size_t)(wv * (CHB / 4) + c) * (SS * WW)]);

    __shared__ float hs[4][WW];
    hs[wv][lane] = h;
    __syncthreads();

    if (wv == 0) {
        float acc = (float)NN * b2[lane];
#pragma unroll
        for (int w = 0; w < WW; ++w) {
            float hw = (hs[0][w] + hs[1][w]) + (hs[2][w] + hs[3][w]);
            acc = fmaf(hw, W2[w * PP + lane], acc);
        }
        out[row * PP + lane] = acc;
    }
}

extern "C" void kernel_launch(void* const* d_in, const int* in_sizes, int n_in,
                              void* d_out, int out_size, void* d_ws, size_t ws_size,
                              hipStream_t stream) {
    const float* x  = (const float*)d_in[0];
    const float* W1 = (const float*)d_in[1];
    const float* b1 = (const float*)d_in[2];
    const float* W2 = (const float*)d_in[3];
    const float* b2 = (const float*)d_in[4];
    float* out  = (float*)d_out;
    float* part = (float*)d_ws;  // BB*CHB * SS*WW floats = 8 MiB

    pool1<<<dim3(BB * CHB), dim3(256), 0, stream>>>(x, W1, b1, part);
    pool2<<<dim3(BB * SS), dim3(256), 0, stream>>>(part, W2, b2, out);
}

// Round 5
// 33.996 us; speedup vs baseline: 1.1150x; 1.1150x over previous
//
#include <hip/hip_runtime.h>
#include <hip/hip_bf16.h>

// Problem constants
#define BB 32   // batch
#define NN 512  // ragged items (reduced axis)
#define SS 32   // static input size (rows per token tile)
#define WW 64   // attention layer width (K of GEMM1, also hidden width)
#define PP 64   // layer param (output features)

#define NCHUNK 16              // n's per block
#define CHB    (NN / NCHUNK)   // 32 chunks per b

typedef __attribute__((ext_vector_type(8))) short bf16x8;  // 8 bf16 (4 VGPRs)
typedef __attribute__((ext_vector_type(4))) float f32x4;   // MFMA acc / vec loads

typedef __attribute__((address_space(1))) const void* as1cv;
typedef __attribute__((address_space(3))) void* as3v;

// f32 -> bf16 via native cast; compiler emits v_cvt_pk_bf16_f32 pairs
__device__ __forceinline__ short f2bf(float v) {
    __hip_bfloat16 h = __float2bfloat16(v);
    return __builtin_bit_cast(short, h);
}

// Kernel 1: part[bid][s][w] = sum_{n in chunk} relu(x[b,n,s,:] @ W1[:,w] + b1[w])
// 1024 blocks x 256 threads (4 waves), 4 tokens/wave.
// Per-wave private LDS double buffer filled by global_load_lds (16B/lane),
// counted vmcnt waits -> one full 8KB token always in flight per wave.
// LDS layout is fragment-major: chunk k (k = mt*4+ks*2+half) at [k*256 + lane*4]
// floats, so ds_read_b128 at lane*16 stride is conflict-free; the fragment
// permutation is baked into the per-lane GLOBAL source address.
__global__ __launch_bounds__(256) void pool1(const float* __restrict__ x,
                                             const float* __restrict__ W1,
                                             const float* __restrict__ b1,
                                             float* __restrict__ part) {
    __shared__ float stg[4][2][2048];   // 64 KiB: [wave][dbuf][8KB token]

    const int tid  = threadIdx.x;
    const int wv   = tid >> 6;
    const int lane = tid & 63;
    const int g    = lane >> 4;       // lane group 0..3
    const int q    = lane & 15;
    const int b     = blockIdx.x >> 5;   // CHB == 32
    const int chunk = blockIdx.x & 31;

    // W1 fragments (B operand): wfrag[nt][ks] elem j = W1[ks*32+g*8+j][nt*16+q]
    bf16x8 wfrag[4][2];
#pragma unroll
    for (int nt = 0; nt < 4; ++nt) {
#pragma unroll
        for (int ks = 0; ks < 2; ++ks) {
            bf16x8 f;
#pragma unroll
            for (int j = 0; j < 8; ++j)
                f[j] = f2bf(W1[(ks * 32 + g * 8 + j) * WW + nt * 16 + q]);
            wfrag[nt][ks] = f;
        }
    }

    // bias folded into MFMA C-init (D col = nt*16+q for all 4 regs)
    f32x4 biasv[4];
#pragma unroll
    for (int nt = 0; nt < 4; ++nt) {
        float bv = b1[nt * 16 + q];
        biasv[nt] = (f32x4){bv, bv, bv, bv};
    }

    f32x4 hrun[2][4];
#pragma unroll
    for (int mt = 0; mt < 2; ++mt)
#pragma unroll
        for (int nt = 0; nt < 4; ++nt)
            hrun[mt][nt] = (f32x4){0.f, 0.f, 0.f, 0.f};

    // clean vmem slate so counted vmcnt below is exact
    asm volatile("s_waitcnt vmcnt(0)" ::: "memory");
    __builtin_amdgcn_sched_barrier(0);

    const float* tok0 = x + ((size_t)(b * NN + chunk * NCHUNK + wv * 4)) * (SS * WW);

    // stage token t into stg[wv][dbuf]: 8 x global_load_lds, 16B per lane
    auto STAGE = [&](int dbuf, int t) {
#pragma unroll
        for (int k = 0; k < 8; ++k) {
            const int mt = k >> 2, ks = (k >> 1) & 1, half = k & 1;
            const float* src = tok0 + (size_t)t * (SS * WW)
                             + (mt * 16 + q) * WW + ks * 32 + g * 8 + half * 4;
            __builtin_amdgcn_global_load_lds((as1cv)src, (as3v)&stg[wv][dbuf][k * 256],
                                             16, 0, 0);
        }
    };

    // consume one staged token: conflict-free ds_read_b128, cvt, 8 MFMA, relu-acc
    auto COMPUTE = [&](int dbuf) {
        f32x4 c[8];
#pragma unroll
        for (int k = 0; k < 8; ++k)
            c[k] = *reinterpret_cast<const f32x4*>(&stg[wv][dbuf][k * 256 + lane * 4]);
        bf16x8 afrag[2][2];
#pragma unroll
        for (int mt = 0; mt < 2; ++mt) {
#pragma unroll
            for (int ks = 0; ks < 2; ++ks) {
                f32x4 lo = c[mt * 4 + ks * 2 + 0];
                f32x4 hi = c[mt * 4 + ks * 2 + 1];
                bf16x8 f;
                f[0] = f2bf(lo[0]); f[1] = f2bf(lo[1]); f[2] = f2bf(lo[2]); f[3] = f2bf(lo[3]);
                f[4] = f2bf(hi[0]); f[5] = f2bf(hi[1]); f[6] = f2bf(hi[2]); f[7] = f2bf(hi[3]);
                afrag[mt][ks] = f;
            }
        }
#pragma unroll
        for (int mt = 0; mt < 2; ++mt) {
#pragma unroll
            for (int nt = 0; nt < 4; ++nt) {
                f32x4 acc = biasv[nt];
                acc = __builtin_amdgcn_mfma_f32_16x16x32_bf16(afrag[mt][0], wfrag[nt][0], acc, 0, 0, 0);
                acc = __builtin_amdgcn_mfma_f32_16x16x32_bf16(afrag[mt][1], wfrag[nt][1], acc, 0, 0, 0);
#pragma unroll
                for (int r = 0; r < 4; ++r)
                    hrun[mt][nt][r] += fmaxf(acc[r], 0.f);
            }
        }
    };

    STAGE(0, 0);
    STAGE(1, 1);
    asm volatile("s_waitcnt vmcnt(8)" ::: "memory");   // tok0 landed
    __builtin_amdgcn_sched_barrier(0);
    COMPUTE(0);
    STAGE(0, 2);
    asm volatile("s_waitcnt vmcnt(8)" ::: "memory");   // tok1 landed
    __builtin_amdgcn_sched_barrier(0);
    COMPUTE(1);
    STAGE(1, 3);
    asm volatile("s_waitcnt vmcnt(8)" ::: "memory");   // tok2 landed
    __builtin_amdgcn_sched_barrier(0);
    COMPUTE(0);
    asm volatile("s_waitcnt vmcnt(0)" ::: "memory");   // tok3 landed
    __builtin_amdgcn_sched_barrier(0);
    COMPUTE(1);

    // cross-wave reduce: reuse stg[wv][0] (8KB/wave) as the reduce buffer
    float* red = &stg[wv][0][0];
#pragma unroll
    for (int mt = 0; mt < 2; ++mt)
#pragma unroll
        for (int nt = 0; nt < 4; ++nt)
#pragma unroll
            for (int r = 0; r < 4; ++r)
                red[(mt * 16 + g * 4 + r) * WW + nt * 16 + q] = hrun[mt][nt][r];
    __syncthreads();

    float* dst = part + (size_t)blockIdx.x * (SS * WW);
#pragma unroll
    for (int k = 0; k < 2; ++k) {
        const int idx = tid * 4 + k * 1024;
        f32x4 v0 = *reinterpret_cast<const f32x4*>(&stg[0][0][idx]);
        f32x4 v1 = *reinterpret_cast<const f32x4*>(&stg[1][0][idx]);
        f32x4 v2 = *reinterpret_cast<const f32x4*>(&stg[2][0][idx]);
        f32x4 v3 = *reinterpret_cast<const f32x4*>(&stg[3][0][idx]);
        f32x4 s = (v0 + v1) + (v2 + v3);
        *reinterpret_cast<f32x4*>(&dst[idx]) = s;
    }
}

// Kernel 2: out[b,s,p] = sum_w (sum_c part[b*32+c][s][w]) * W2[w,p] + NN * b2[p]
// 1024 blocks (one per output row), 4 waves split the 32-chunk reduction.
__global__ __launch_bounds__(256) void pool2(const float* __restrict__ part,
                                             const float* __restrict__ W2,
                                             const float* __restrict__ b2,
                                             float* __restrict__ out) {
    const int tid  = threadIdx.x;
    const int wv   = tid >> 6;
    const int lane = tid & 63;
    const int row  = blockIdx.x;        // b*SS + s
    const int b    = row >> 5;          // SS == 32
    const int s    = row & 31;

    const float* pb = part + ((size_t)b * CHB) * (SS * WW) + s * WW + lane;
    float h = 0.f;
#pragma unroll
    for (int c = 0; c < CHB / 4; ++c)
        h += pb[(size_t)(wv * (CHB / 4) + c) * (SS * WW)];

    __shared__ float hs[4][WW];
    hs[wv][lane] = h;
    __syncthreads();

    if (wv == 0) {
        float acc = (float)NN * b2[lane];
#pragma unroll
        for (int w = 0; w < WW; ++w) {
            float hw = (hs[0][w] + hs[1][w]) + (hs[2][w] + hs[3][w]);
            acc = fmaf(hw, W2[w * PP + lane], acc);
        }
        out[row * PP + lane] = acc;
    }
}

extern "C" void kernel_launch(void* const* d_in, const int* in_sizes, int n_in,
                              void* d_out, int out_size, void* d_ws, size_t ws_size,
                              hipStream_t stream) {
    const float* x  = (const float*)d_in[0];
    const float* W1 = (const float*)d_in[1];
    const float* b1 = (const float*)d_in[2];
    const float* W2 = (const float*)d_in[3];
    const float* b2 = (const float*)d_in[4];
    float* out  = (float*)d_out;
    float* part = (float*)d_ws;  // BB*CHB * SS*WW floats = 8 MiB

    pool1<<<dim3(BB * CHB), dim3(256), 0, stream>>>(x, W1, b1, part);
    pool2<<<dim3(BB * SS), dim3(256), 0, stream>>>(part, W2, b2, out);
}

// Round 6
// 33.040 us; speedup vs baseline: 1.1473x; 1.0289x over previous
//
#include <hip/hip_runtime.h>
#include <hip/hip_bf16.h>

// Problem constants
#define BB 32   // batch
#define NN 512  // ragged items (reduced axis)
#define SS 32   // static input size (rows per token tile)
#define WW 64   // attention layer width (K of GEMM1, also hidden width)
#define PP 64   // layer param (output features)

#define NCHUNK 16              // n's per block
#define CHB    (NN / NCHUNK)   // 32 chunks per b

typedef __attribute__((ext_vector_type(8))) short bf16x8;  // 8 bf16 (4 VGPRs)
typedef __attribute__((ext_vector_type(4))) float f32x4;   // MFMA acc / vec loads

typedef __attribute__((address_space(1))) const void* as1cv;
typedef __attribute__((address_space(3))) void* as3v;

// f32 -> bf16 via native cast; compiler emits v_cvt_pk_bf16_f32 pairs
__device__ __forceinline__ short f2bf(float v) {
    __hip_bfloat16 h = __float2bfloat16(v);
    return __builtin_bit_cast(short, h);
}

// Kernel 1: part[bid][s][w] = sum_{n in chunk} relu(x[b,n,s,:] @ W1[:,w] + b1[w])
// 1024 blocks x 256 threads (4 waves), 4 tokens/wave.
// Per-wave private LDS double buffer filled by global_load_lds (16B/lane) with
// LINEAR per-lane sources: each instruction reads one contiguous 1KB span of
// the token (100% sector efficiency). LDS holds an exact row-major image of
// the 32x64 f32 token; MFMA A-fragments are gathered by ds_read_b128 (the
// ~16-lane bank aliasing costs ~128 cyc/token vs the 800-cyc memory budget).
__global__ __launch_bounds__(256) void pool1(const float* __restrict__ x,
                                             const float* __restrict__ W1,
                                             const float* __restrict__ b1,
                                             float* __restrict__ part) {
    __shared__ float stg[4][2][2048];   // 64 KiB: [wave][dbuf][8KB token image]

    const int tid  = threadIdx.x;
    const int wv   = tid >> 6;
    const int lane = tid & 63;
    const int g    = lane >> 4;       // lane group 0..3
    const int q    = lane & 15;
    const int b     = blockIdx.x >> 5;   // CHB == 32
    const int chunk = blockIdx.x & 31;

    // W1 fragments (B operand): wfrag[nt][ks] elem j = W1[ks*32+g*8+j][nt*16+q]
    bf16x8 wfrag[4][2];
#pragma unroll
    for (int nt = 0; nt < 4; ++nt) {
#pragma unroll
        for (int ks = 0; ks < 2; ++ks) {
            bf16x8 f;
#pragma unroll
            for (int j = 0; j < 8; ++j)
                f[j] = f2bf(W1[(ks * 32 + g * 8 + j) * WW + nt * 16 + q]);
            wfrag[nt][ks] = f;
        }
    }

    // bias folded into MFMA C-init (D col = nt*16+q for all 4 regs)
    f32x4 biasv[4];
#pragma unroll
    for (int nt = 0; nt < 4; ++nt) {
        float bv = b1[nt * 16 + q];
        biasv[nt] = (f32x4){bv, bv, bv, bv};
    }

    f32x4 hrun[2][4];
#pragma unroll
    for (int mt = 0; mt < 2; ++mt)
#pragma unroll
        for (int nt = 0; nt < 4; ++nt)
            hrun[mt][nt] = (f32x4){0.f, 0.f, 0.f, 0.f};

    // clean vmem slate so counted vmcnt below is exact
    asm volatile("s_waitcnt vmcnt(0)" ::: "memory");
    __builtin_amdgcn_sched_barrier(0);

    const float* tok0 = x + ((size_t)(b * NN + chunk * NCHUNK + wv * 4)) * (SS * WW);

    // stage token t into stg[wv][dbuf]: 8 x global_load_lds, each one
    // contiguous 1KB wave request (lane L -> bytes [k*1024 + L*16, +16))
    auto STAGE = [&](int dbuf, int t) {
        const float* tbase = tok0 + (size_t)t * (SS * WW);
#pragma unroll
        for (int k = 0; k < 8; ++k) {
            const float* src = tbase + k * 256 + lane * 4;
            __builtin_amdgcn_global_load_lds((as1cv)src, (as3v)&stg[wv][dbuf][k * 256],
                                             16, 0, 0);
        }
    };

    // consume one staged token: fragment-gather ds_read_b128, cvt, 8 MFMA, relu-acc
    auto COMPUTE = [&](int dbuf) {
        const char* base = (const char*)&stg[wv][dbuf][0];
        bf16x8 afrag[2][2];
#pragma unroll
        for (int mt = 0; mt < 2; ++mt) {
#pragma unroll
            for (int ks = 0; ks < 2; ++ks) {
                // afrag elem j = x[row = mt*16+q][col = ks*32 + g*8 + j]
                const unsigned o = (unsigned)((mt * 16 + q) * 256 + ks * 128 + g * 32);
                f32x4 lo = *reinterpret_cast<const f32x4*>(base + o);
                f32x4 hi = *reinterpret_cast<const f32x4*>(base + o + 16);
                bf16x8 f;
                f[0] = f2bf(lo[0]); f[1] = f2bf(lo[1]); f[2] = f2bf(lo[2]); f[3] = f2bf(lo[3]);
                f[4] = f2bf(hi[0]); f[5] = f2bf(hi[1]); f[6] = f2bf(hi[2]); f[7] = f2bf(hi[3]);
                afrag[mt][ks] = f;
            }
        }
#pragma unroll
        for (int mt = 0; mt < 2; ++mt) {
#pragma unroll
            for (int nt = 0; nt < 4; ++nt) {
                f32x4 acc = biasv[nt];
                acc = __builtin_amdgcn_mfma_f32_16x16x32_bf16(afrag[mt][0], wfrag[nt][0], acc, 0, 0, 0);
                acc = __builtin_amdgcn_mfma_f32_16x16x32_bf16(afrag[mt][1], wfrag[nt][1], acc, 0, 0, 0);
#pragma unroll
                for (int r = 0; r < 4; ++r)
                    hrun[mt][nt][r] += fmaxf(acc[r], 0.f);
            }
        }
    };

    STAGE(0, 0);
    STAGE(1, 1);
    asm volatile("s_waitcnt vmcnt(8)" ::: "memory");   // tok0 landed
    __builtin_amdgcn_sched_barrier(0);
    COMPUTE(0);
    STAGE(0, 2);
    asm volatile("s_waitcnt vmcnt(8)" ::: "memory");   // tok1 landed
    __builtin_amdgcn_sched_barrier(0);
    COMPUTE(1);
    STAGE(1, 3);
    asm volatile("s_waitcnt vmcnt(8)" ::: "memory");   // tok2 landed
    __builtin_amdgcn_sched_barrier(0);
    COMPUTE(0);
    asm volatile("s_waitcnt vmcnt(0)" ::: "memory");   // tok3 landed
    __builtin_amdgcn_sched_barrier(0);
    COMPUTE(1);

    // cross-wave reduce: reuse stg[wv][0] (8KB/wave) as the reduce buffer
    float* red = &stg[wv][0][0];
#pragma unroll
    for (int mt = 0; mt < 2; ++mt)
#pragma unroll
        for (int nt = 0; nt < 4; ++nt)
#pragma unroll
            for (int r = 0; r < 4; ++r)
                red[(mt * 16 + g * 4 + r) * WW + nt * 16 + q] = hrun[mt][nt][r];
    __syncthreads();

    float* dst = part + (size_t)blockIdx.x * (SS * WW);
#pragma unroll
    for (int k = 0; k < 2; ++k) {
        const int idx = tid * 4 + k * 1024;
        f32x4 v0 = *reinterpret_cast<const f32x4*>(&stg[0][0][idx]);
        f32x4 v1 = *reinterpret_cast<const f32x4*>(&stg[1][0][idx]);
        f32x4 v2 = *reinterpret_cast<const f32x4*>(&stg[2][0][idx]);
        f32x4 v3 = *reinterpret_cast<const f32x4*>(&stg[3][0][idx]);
        f32x4 s = (v0 + v1) + (v2 + v3);
        *reinterpret_cast<f32x4*>(&dst[idx]) = s;
    }
}

// Kernel 2: out[b,s,p] = sum_w (sum_c part[b*32+c][s][w]) * W2[w,p] + NN * b2[p]
// 1024 blocks (one per output row), 4 waves split the 32-chunk reduction.
__global__ __launch_bounds__(256) void pool2(const float* __restrict__ part,
                                             const float* __restrict__ W2,
                                             const float* __restrict__ b2,
                                             float* __restrict__ out) {
    const int tid  = threadIdx.x;
    const int wv   = tid >> 6;
    const int lane = tid & 63;
    const int row  = blockIdx.x;        // b*SS + s
    const int b    = row >> 5;          // SS == 32
    const int s    = row & 31;

    const float* pb = part + ((size_t)b * CHB) * (SS * WW) + s * WW + lane;
    float h = 0.f;
#pragma unroll
    for (int c = 0; c < CHB / 4; ++c)
        h += pb[(size_t)(wv * (CHB / 4) + c) * (SS * WW)];

    __shared__ float hs[4][WW];
    hs[wv][lane] = h;
    __syncthreads();

    if (wv == 0) {
        float acc = (float)NN * b2[lane];
#pragma unroll
        for (int w = 0; w < WW; ++w) {
            float hw = (hs[0][w] + hs[1][w]) + (hs[2][w] + hs[3][w]);
            acc = fmaf(hw, W2[w * PP + lane], acc);
        }
        out[row * PP + lane] = acc;
    }
}

extern "C" void kernel_launch(void* const* d_in, const int* in_sizes, int n_in,
                              void* d_out, int out_size, void* d_ws, size_t ws_size,
                              hipStream_t stream) {
    const float* x  = (const float*)d_in[0];
    const float* W1 = (const float*)d_in[1];
    const float* b1 = (const float*)d_in[2];
    const float* W2 = (const float*)d_in[3];
    const float* b2 = (const float*)d_in[4];
    float* out  = (float*)d_out;
    float* part = (float*)d_ws;  // BB*CHB * SS*WW floats = 8 MiB

    pool1<<<dim3(BB * CHB), dim3(256), 0, stream>>>(x, W1, b1, part);
    pool2<<<dim3(BB * SS), dim3(256), 0, stream>>>(part, W2, b2, out);
}